// Round 8
// baseline (229.063 us; speedup 1.0000x reference)
//
#include <hip/hip_runtime.h>
#include <hip/hip_bf16.h>

typedef _Float16 f16x8 __attribute__((ext_vector_type(8)));
typedef float f32x4 __attribute__((ext_vector_type(4)));
typedef unsigned short u16;
typedef u16 u16x8 __attribute__((ext_vector_type(8)));
typedef u16 u16x4 __attribute__((ext_vector_type(4)));

// ---------- fp16 <-> fp32 helpers ----------
__device__ __forceinline__ u16 f2h_bits(float f) {
    _Float16 h = (_Float16)f;           // RNE
    return __builtin_bit_cast(u16, h);
}
__device__ __forceinline__ float h2f(u16 b) {
    return (float)__builtin_bit_cast(_Float16, b);
}

// ---------- async global->LDS, 16B per lane ----------
__device__ __forceinline__ void async_ld16(const void* g, void* l) {
    __builtin_amdgcn_global_load_lds(
        (__attribute__((address_space(1))) void*)(void*)g,
        (__attribute__((address_space(3))) void*)l,
        16, 0, 0);
}

// =====================================================================
// GEMM: C[M,N] = alpha * A[M,K] * Bt[N,K]^T  (fp16 bits, row-major
// k-contiguous). BM=BN=128, BK=32, 256 threads (4 waves, 2x2 grid, each
// wave 64x64 via 4x4 mfma_f32_16x16x32_f16 -> 16 MFMA per k-step).
//
// ROUND-8 K-LOOP (round-7 lesson: __syncthreads == s_waitcnt vmcnt(0)
// + s_barrier, which force-drains ANY prefetch): raw s_barrier + manual
// s_waitcnt vmcnt(4) + global_load_lds DMA staging into TRIPLE-buffered
// LDS, issue-ahead-2. One barrier per k-step, vmcnt never drained to 0
// (the AITER/hipBLASLt pattern).
//
//   step k: s_waitcnt vmcnt(4)  // my tile-k DMAs landed (k+1's stay in flight)
//           s_barrier           // everyone's landed; buf[k-1] readers done
//           issue 4 DMAs tile k+2 -> buf[(k+2)%3]  (== buf holding k-1)
//           8 x ds_read_b128 + 16 x MFMA on buf[k%3]
//
// Safety: readers of tile k-1 completed their ds_reads (reg-dep lgkm
// waits before MFMA) before reaching barrier k, so overwriting that
// buffer after barrier k is race-free regardless of DMA landing time.
//
// LDS 4-seg XOR swizzle (round-2 proven, 0 conflicts): LDS[row][p] =
// G-seg p^((row>>1)&3); DMA is lane-linear on the LDS side so the
// swizzle is applied to the fetched GLOBAL segment; fragment reads use
// p = quad^((l16>>1)&3).
//
// XCD mapping: lin=by*GX+bx, xcd=lin&7; 2D panels bnW x bmW per XCD
// sized so the concurrent working set ~fits 4MiB L2 (r5: FETCH 135->32MB).
//
// MODE: 0 = plain u16 store; 1 = EXPSUM (store exp(alpha*s), atomicAdd
// row sums); 2 = QKV (bn<16 -> QK store; bn>=16 -> write V transposed
// into vt[1024][4096]).
//
// Requires Ksplit % 32 == 0, Ksplit >= 96. gridDim.z = split-K.
// =====================================================================
template <int MODE>
__global__ __launch_bounds__(256, 3) void gemm_bt(
    const u16* __restrict__ A, int lda,
    const u16* __restrict__ B, int ldb,
    u16* __restrict__ C, int ldc,
    int Ksplit, float alpha, size_t c_z_stride,
    int bnW, int bmW, int numPanelX,
    float* __restrict__ rowsum, u16* __restrict__ vt)
{
    // 3 buffers x (A 4096 u16 + B 4096 u16) = 48 KB
    __shared__ __attribute__((aligned(16))) u16 L[3 * 8192];

    const int t    = threadIdx.x;
    const int lane = t & 63;
    const int wave = t >> 6;
    const int wm   = wave & 1;
    const int wn   = wave >> 1;
    const int l16  = lane & 15;
    const int quad = lane >> 4;

    // 2D-panel XCD mapping (grid x*y divisible by 8)
    const int lin = blockIdx.y * gridDim.x + blockIdx.x;
    const int xcd = lin & 7;
    const int idx = lin >> 3;
    const int px  = xcd % numPanelX;
    const int py  = xcd / numPanelX;
    const int bn  = px * bnW + idx % bnW;
    const int bm  = py * bmW + idx / bnW;

    const int kz = blockIdx.z;
    A += (size_t)kz * Ksplit;
    B += (size_t)kz * Ksplit;
    C += (size_t)kz * c_z_stride;

    // DMA staging: thread t covers rows (t>>2) and (t>>2)+64, LDS slot
    // t*8 within the A (or B) region; fetches swizzled global segment.
    const int srow = t >> 2;
    const int scol = ((t & 3) ^ ((t >> 3) & 3)) * 8;

    const u16* Ag = A + (size_t)(bm * 128 + srow) * lda + scol;
    const u16* Bg = B + (size_t)(bn * 128 + srow) * ldb + scol;
    const size_t a64 = (size_t)64 * lda;   // row+64: same swizzle term
    const size_t b64 = (size_t)64 * ldb;

    u16* l0 = L;
    u16* l1 = L + 8192;
    u16* l2 = L + 16384;

    // fragment base offsets within a buffer (u16 units)
    const int fseg = (quad ^ ((l16 >> 1) & 3)) * 8;
    const int AfrO = (wm * 64 + l16) * 32 + fseg;
    const int BfrO = 4096 + (wn * 64 + l16) * 32 + fseg;

    f32x4 acc[4][4] = {};

    // issue one tile's 4 DMAs (per thread) into buffer buf
    auto issue = [&](int koff, u16* buf) {
        async_ld16(Ag + koff,       buf + t * 8);
        async_ld16(Ag + koff + a64, buf + 2048 + t * 8);
        async_ld16(Bg + koff,       buf + 4096 + t * 8);
        async_ld16(Bg + koff + b64, buf + 6144 + t * 8);
    };

    // prologue: tiles 0,1
    issue(0, l0);
    issue(32, l1);

    u16 *cur = l0, *nxt = l1, *prv = l2;
    for (int k0 = 0; k0 < Ksplit; k0 += 32) {
        __builtin_amdgcn_s_waitcnt(0xF74);   // vmcnt(4): tile-k DMAs landed
        __builtin_amdgcn_s_barrier();        // all waves landed; prv readers done

        int kf = k0 + 64;                    // tile k+2 (wraps at tail; harmless)
        if (kf >= Ksplit) kf -= Ksplit;
        issue(kf, prv);

        f16x8 af[4], bfv[4];
#pragma unroll
        for (int i = 0; i < 4; i++) af[i]  = *(const f16x8*)(cur + AfrO + i * 512);
#pragma unroll
        for (int i = 0; i < 4; i++) bfv[i] = *(const f16x8*)(cur + BfrO + i * 512);
#pragma unroll
        for (int mi = 0; mi < 4; mi++)
#pragma unroll
            for (int ni = 0; ni < 4; ni++)
                acc[mi][ni] = __builtin_amdgcn_mfma_f32_16x16x32_f16(
                    af[mi], bfv[ni], acc[mi][ni], 0, 0, 0);

        u16* tmp = cur; cur = nxt; nxt = prv; prv = tmp;
    }

    // epilogue: C/D layout col = lane&15, row = quad*4 + reg
    const int crow = bm * 128 + wm * 64 + quad * 4;
    const int ccol = bn * 128 + wn * 64 + l16;

    if (MODE == 1) {
        float rs[4][4];
#pragma unroll
        for (int mi = 0; mi < 4; mi++)
#pragma unroll
            for (int r = 0; r < 4; r++) rs[mi][r] = 0.f;
#pragma unroll
        for (int mi = 0; mi < 4; mi++) {
#pragma unroll
            for (int ni = 0; ni < 4; ni++) {
#pragma unroll
                for (int r = 0; r < 4; r++) {
                    float e = __expf(acc[mi][ni][r] * alpha);
                    rs[mi][r] += e;
                    C[(size_t)(crow + mi * 16 + r) * ldc + (ccol + ni * 16)] = f2h_bits(e);
                }
            }
        }
#pragma unroll
        for (int mi = 0; mi < 4; mi++) {
#pragma unroll
            for (int r = 0; r < 4; r++) {
                float s = rs[mi][r];
#pragma unroll
                for (int o = 1; o < 16; o <<= 1) s += __shfl_xor(s, o);
                if (l16 == 0)
                    atomicAdd(&rowsum[crow + mi * 16 + r], s);
            }
        }
    } else if (MODE == 2 && bn >= 16) {
        // V tile -> write transposed into vt[1024][4096]
#pragma unroll
        for (int ni = 0; ni < 4; ni++) {
            const int cV = (bn - 16) * 128 + wn * 64 + ni * 16 + l16;
#pragma unroll
            for (int mi = 0; mi < 4; mi++) {
                u16x4 o;
#pragma unroll
                for (int r = 0; r < 4; r++) o[r] = f2h_bits(acc[mi][ni][r]);
                *(u16x4*)(vt + (size_t)cV * 4096 + crow + mi * 16) = o;
            }
        }
    } else {
#pragma unroll
        for (int mi = 0; mi < 4; mi++)
#pragma unroll
            for (int ni = 0; ni < 4; ni++)
#pragma unroll
                for (int r = 0; r < 4; r++)
                    C[(size_t)(crow + mi * 16 + r) * ldc + (ccol + ni * 16)] =
                        f2h_bits(acc[mi][ni][r] * alpha);
    }
}

// =====================================================================
// cast fp32 -> fp16 bits, 4 elems/thread
// =====================================================================
__global__ __launch_bounds__(256) void cast_to_f16(
    const float* __restrict__ in, u16* __restrict__ out, int n)
{
    int i = (blockIdx.x * 256 + threadIdx.x) * 4;
    if (i + 3 < n) {
        float4 v = *(const float4*)(in + i);
        ushort4 o;
        o.x = f2h_bits(v.x);
        o.y = f2h_bits(v.y);
        o.z = f2h_bits(v.z);
        o.w = f2h_bits(v.w);
        *(ushort4*)(out + i) = o;
    }
}

// =====================================================================
// transpose the 3 weight matrices [1024][1024] fp32 -> packed fp16
// Wt[3072][1024]; z selects the matrix. 32x32 LDS tile, block (32,8).
// =====================================================================
__global__ __launch_bounds__(256) void transpose_w3(
    const float* __restrict__ W0, const float* __restrict__ W1,
    const float* __restrict__ W2, u16* __restrict__ out)
{
    const float* in = (blockIdx.z == 0) ? W0 : (blockIdx.z == 1) ? W1 : W2;
    u16* o = out + (size_t)blockIdx.z * 1024 * 1024;
    __shared__ float tile[32][33];
    const int bx = blockIdx.x * 32;
    const int by = blockIdx.y * 32;
    const int tx = threadIdx.x, ty = threadIdx.y;
#pragma unroll
    for (int j = 0; j < 4; j++)
        tile[ty + j * 8][tx] = in[(size_t)(by + ty + j * 8) * 1024 + bx + tx];
    __syncthreads();
#pragma unroll
    for (int j = 0; j < 4; j++)
        o[(size_t)(bx + ty + j * 8) * 1024 + by + tx] = f2h_bits(tile[tx][ty + j * 8]);
}

// =====================================================================
// zero a float array (n multiple of 1024)
// =====================================================================
__global__ __launch_bounds__(256) void zero_f32(float* __restrict__ p, int n)
{
    int i = (blockIdx.x * 256 + threadIdx.x) * 4;
    if (i + 3 < n) *(float4*)(p + i) = float4{0.f, 0.f, 0.f, 0.f};
}

// =====================================================================
// out = (P0+P1+P2+P3)/l[row]; partials fp16, 8 elems/thread
// =====================================================================
__global__ __launch_bounds__(256) void add_div4(
    const u16* __restrict__ P, const float* __restrict__ l,
    float* __restrict__ o)
{
    const size_t zs = (size_t)4096 * 1024;
    int i = (blockIdx.x * 256 + threadIdx.x) * 8;
    float inv = 1.0f / l[i >> 10];
    float s[8] = {};
#pragma unroll
    for (int z = 0; z < 4; z++) {
        u16x8 h = *(const u16x8*)(P + z * zs + i);
#pragma unroll
        for (int j = 0; j < 8; j++) s[j] += h2f(h[j]);
    }
    float4 lo{s[0] * inv, s[1] * inv, s[2] * inv, s[3] * inv};
    float4 hi{s[4] * inv, s[5] * inv, s[6] * inv, s[7] * inv};
    *(float4*)(o + i) = lo;
    *(float4*)(o + i + 4) = hi;
}

// =====================================================================
// launch
//
// Workspace liveness (MiB):
//   xb [0,8)    live 1-3          Wt [8,14)  live 2-3
//   QK [14,30)  live 3-5          Vt [64,72) live 3-6
//   Sb [32,64)  live 5-6          lr [72,+16K) zero 4, atomics 5, read 7
//   P  [0,32)   written 6 (xb/Wt/QK dead), read 7
// =====================================================================
extern "C" void kernel_launch(void* const* d_in, const int* in_sizes, int n_in,
                              void* d_out, int out_size, void* d_ws, size_t ws_size,
                              hipStream_t stream)
{
    (void)in_sizes; (void)n_in; (void)out_size; (void)ws_size;
    const float* x  = (const float*)d_in[0];
    const float* Wq = (const float*)d_in[1];
    const float* Wk = (const float*)d_in[2];
    const float* Wv = (const float*)d_in[3];
    float* out = (float*)d_out;
    char* ws = (char*)d_ws;

    u16* xb  = (u16*)(ws);                              //  8 MiB
    u16* Wt  = (u16*)(ws + ((size_t)8  << 20));         //  6 MiB
    u16* QK  = (u16*)(ws + ((size_t)14 << 20));         // 16 MiB [4096][2048]
    u16* Sb  = (u16*)(ws + ((size_t)32 << 20));         // 32 MiB [4096][4096]
    u16* Vt  = (u16*)(ws + ((size_t)64 << 20));         //  8 MiB [1024][4096]
    float* lr = (float*)(ws + ((size_t)72 << 20));      // 16 KiB row sums
    u16* P   = (u16*)(ws);                              // 32 MiB: 4 x [4096][1024]

    const int S = 4096, D = 1024;
    dim3 tb(32, 8);

    // 1) cast x to fp16
    cast_to_f16<<<(S * D) / (4 * 256), 256, 0, stream>>>(x, xb, S * D);

    // 2) transpose-cast all three W's into packed Wt[3072][1024]
    transpose_w3<<<dim3(32, 32, 3), tb, 0, stream>>>(Wq, Wk, Wv, Wt);

    // 3) [Q|K] = x @ [Wq|Wk], V^T written directly (M=4096, N=3072, K=1024)
    gemm_bt<2><<<dim3(3072 / 128, S / 128, 1), 256, 0, stream>>>(
        xb, D, Wt, D, QK, 2048, D, 1.0f, 0, 6, 16, 4, nullptr, Vt);

    // 4) zero row-sum accumulator
    zero_f32<<<S / (4 * 256), 256, 0, stream>>>(lr, S);

    // 5) Sb = exp((Q @ K^T)/32) + rowsum atomics  (M=N=4096, K=1024)
    gemm_bt<1><<<dim3(S / 128, S / 128, 1), 256, 0, stream>>>(
        QK, 2048, QK + 1024, 2048, Sb, S, D, 0.03125f, 0, 8, 16, 4, lr, nullptr);

    // 6) P[z] = expS @ V, split-K=4 (M=4096, N=1024, Ksplit=1024)
    gemm_bt<0><<<dim3(D / 128, S / 128, 4), 256, 0, stream>>>(
        Sb, S, Vt, S, P, D, 1024, 1.0f, (size_t)S * D, 4, 8, 2, nullptr, nullptr);

    // 7) out = (P0+P1+P2+P3) / l[row]
    add_div4<<<(S * D) / (8 * 256), 256, 0, stream>>>(P, lr, out);
}